// Round 1
// baseline (24084.267 us; speedup 1.0000x reference)
//
#include <hip/hip_runtime.h>
#include <math.h>

// ---------------------------------------------------------------------------
// TimeSeriesTransformerDecoder — incremental-decode rewrite (fp32 baseline)
//
// Key simplifications vs reference (exact, not approximate):
//  * KV-cached incremental decoding: step t computes only position t.
//  * Cross-attention has T=1 memory token -> softmax == 1 -> CA output is a
//    per-layer constant  ca_add[l] = (memory @ Wv.T + bv) @ Wo.T + bo.
// ---------------------------------------------------------------------------

#define B   256
#define CTX 512
#define D   512
#define H   8
#define HD  64
#define L   4
#define FF  2048
#define P   24

// ---------------- generic tiled fp32 GEMM:  C[M,N] = A[M,K] @ W[N,K]^T + bias
// EP: 0 = none, 1 = exact gelu.  WRITE_KV: also scatter k/v into caches.
template <int EP, bool WRITE_KV>
__global__ __launch_bounds__(256) void gemm_bias(
    const float* __restrict__ A, const float* __restrict__ W,
    const float* __restrict__ bias, float* __restrict__ C,
    int M, int N, int K,
    float* __restrict__ kc, float* __restrict__ vc, int t)
{
    __shared__ float As[16][68];
    __shared__ float Ws[16][68];
    const int m0 = blockIdx.x * 64;
    const int n0 = blockIdx.y * 64;
    const int tid = threadIdx.x;
    const int tm = tid >> 4;   // 0..15
    const int tn = tid & 15;   // 0..15

    float acc[4][4] = {};

    for (int k0 = 0; k0 < K; k0 += 16) {
#pragma unroll
        for (int i = 0; i < 4; i++) {
            int idx = tid + i * 256;          // 0..1023
            int r = idx >> 4;                 // row in tile 0..63
            int c = idx & 15;                 // k in tile 0..15
            As[c][r] = A[(m0 + r) * K + k0 + c];
            Ws[c][r] = W[(n0 + r) * K + k0 + c];
        }
        __syncthreads();
#pragma unroll
        for (int kk = 0; kk < 16; kk++) {
            float a4[4], w4[4];
            *reinterpret_cast<float4*>(a4) =
                *reinterpret_cast<const float4*>(&As[kk][tm * 4]);
            *reinterpret_cast<float4*>(w4) =
                *reinterpret_cast<const float4*>(&Ws[kk][tn * 4]);
#pragma unroll
            for (int i = 0; i < 4; i++)
#pragma unroll
                for (int j = 0; j < 4; j++)
                    acc[i][j] = fmaf(a4[i], w4[j], acc[i][j]);
        }
        __syncthreads();
    }

#pragma unroll
    for (int i = 0; i < 4; i++) {
        int m = m0 + tm * 4 + i;
#pragma unroll
        for (int j = 0; j < 4; j++) {
            int n = n0 + tn * 4 + j;
            float v = acc[i][j] + bias[n];
            if (EP == 1) v = 0.5f * v * (1.0f + erff(v * 0.70710678118654752f));
            C[m * N + n] = v;
            if (WRITE_KV) {
                if (n >= D) {                       // k or v columns
                    int nn = n - D;
                    float* cache = (nn < D) ? kc : vc;
                    int f = nn & (D - 1);           // feature within k or v
                    int h = f >> 6, hd = f & 63;
                    // cache layout [B][H][P][HD] (per layer)
                    cache[((m * H + h) * P + t) * HD + hd] = v;
                }
            }
        }
    }
}

// ---------------- causal self-attention for the single new position t
// grid: B*H blocks, 64 threads. kc/vc already offset to layer l.
__global__ __launch_bounds__(64) void attn_kernel(
    const float* __restrict__ qkv, const float* __restrict__ kc,
    const float* __restrict__ vc, float* __restrict__ attn_out, int t)
{
    const int blk = blockIdx.x;
    const int b = blk >> 3;
    const int h = blk & 7;
    const int lane = threadIdx.x;

    const float q = qkv[b * (3 * D) + h * HD + lane];
    const float* kb = kc + ((b * H + h) * P) * HD;
    const float* vb = vc + ((b * H + h) * P) * HD;

    float scores[P];
    const int n = t + 1;
#pragma unroll
    for (int j = 0; j < P; j++) {
        if (j < n) {
            float p = q * kb[j * HD + lane];
#pragma unroll
            for (int o = 32; o >= 1; o >>= 1) p += __shfl_xor(p, o);
            scores[j] = p * 0.125f;            // 1/sqrt(64)
        }
    }
    float mx = -1e30f;
#pragma unroll
    for (int j = 0; j < P; j++)
        if (j < n) mx = fmaxf(mx, scores[j]);
    float s = 0.0f;
#pragma unroll
    for (int j = 0; j < P; j++)
        if (j < n) { scores[j] = expf(scores[j] - mx); s += scores[j]; }
    const float inv = 1.0f / s;
    float o = 0.0f;
#pragma unroll
    for (int j = 0; j < P; j++)
        if (j < n) o = fmaf(scores[j], vb[j * HD + lane], o);
    attn_out[b * D + h * HD + lane] = o * inv;
}

// ---------------- fused residual + LN (+ optional const-CA add + second LN)
// block = one batch row, 256 threads, 2 elements/thread
__device__ __forceinline__ float block_sum512(float v, float* sbuf)
{
#pragma unroll
    for (int o = 32; o >= 1; o >>= 1) v += __shfl_xor(v, o);
    const int wid = threadIdx.x >> 6, lane = threadIdx.x & 63;
    if (lane == 0) sbuf[wid] = v;
    __syncthreads();
    v = sbuf[0] + sbuf[1] + sbuf[2] + sbuf[3];
    __syncthreads();
    return v;
}

__global__ __launch_bounds__(256) void fused_ln(
    const float* __restrict__ x, const float* __restrict__ y,
    const float* __restrict__ ca,
    const float* __restrict__ w1, const float* __restrict__ b1,
    const float* __restrict__ w2, const float* __restrict__ b2,
    float* __restrict__ out)
{
    __shared__ float sbuf[4];
    const int b = blockIdx.x;
    const int tid = threadIdx.x;
    const int i0 = b * D + tid, i1 = i0 + 256;

    float r0 = x[i0] + y[i0];
    float r1 = x[i1] + y[i1];

    float m = block_sum512(r0 + r1, sbuf) * (1.0f / D);
    float d0 = r0 - m, d1 = r1 - m;
    float var = block_sum512(d0 * d0 + d1 * d1, sbuf) * (1.0f / D);
    float rstd = rsqrtf(var + 1e-5f);
    float z0 = d0 * rstd * w1[tid] + b1[tid];
    float z1 = d1 * rstd * w1[tid + 256] + b1[tid + 256];

    if (ca != nullptr) {
        r0 = z0 + ca[i0];
        r1 = z1 + ca[i1];
        m = block_sum512(r0 + r1, sbuf) * (1.0f / D);
        d0 = r0 - m; d1 = r1 - m;
        var = block_sum512(d0 * d0 + d1 * d1, sbuf) * (1.0f / D);
        rstd = rsqrtf(var + 1e-5f);
        z0 = d0 * rstd * w2[tid] + b2[tid];
        z1 = d1 * rstd * w2[tid + 256] + b2[tid + 256];
    }
    out[i0] = z0;
    out[i1] = z1;
}

// ---------------- positional encoding table [P][D]
__global__ void pe_kernel(float* __restrict__ pe)
{
    const int t = blockIdx.x;
    const int i = threadIdx.x;                 // 0..255  -> dims 2i, 2i+1
    const float div = expf(-(2.0f * i) * (logf(10000.0f) / (float)D));
    const float a = (float)t * div;
    pe[t * D + 2 * i]     = sinf(a);
    pe[t * D + 2 * i + 1] = cosf(a);
}

__global__ void init_vals(float* __restrict__ vals,
                          const float* __restrict__ start_token)
{
    vals[threadIdx.x] = start_token[0];
}

// ---------------- embedding for position t: x = vals[t]*ve_W + ve_b + pe[t]
__global__ __launch_bounds__(256) void embed_kernel(
    const float* __restrict__ vals, const float* __restrict__ veW,
    const float* __restrict__ veb, const float* __restrict__ pe,
    float* __restrict__ x, int t)
{
    const int idx = blockIdx.x * 256 + threadIdx.x;  // 0 .. B*D-1
    const int b = idx >> 9, d = idx & (D - 1);
    x[idx] = vals[t * B + b] * veW[d] + veb[d] + pe[t * D + d];
}

// ---------------- output head stage 2: nv = h @ o2_w.T + o2_b ; store
__global__ __launch_bounds__(64) void head2_kernel(
    const float* __restrict__ hh, const float* __restrict__ w,
    const float* __restrict__ bias, float* __restrict__ vals,
    float* __restrict__ out, int t)
{
    const int b = blockIdx.x;
    const int lane = threadIdx.x;
    float p = 0.0f;
#pragma unroll
    for (int i = 0; i < 4; i++) p = fmaf(hh[b * 256 + lane + i * 64], w[lane + i * 64], p);
#pragma unroll
    for (int o = 32; o >= 1; o >>= 1) p += __shfl_xor(p, o);
    if (lane == 0) {
        const float v = p + bias[0];
        vals[(t + 1) * B + b] = v;
        out[b * P + t] = v;
    }
}

// ---------------------------------------------------------------------------
extern "C" void kernel_launch(void* const* d_in, const int* in_sizes, int n_in,
                              void* d_out, int out_size, void* d_ws, size_t ws_size,
                              hipStream_t stream)
{
    const float* context     = (const float*)d_in[0];
    const float* start_token = (const float*)d_in[1];
    const float* ctx_W  = (const float*)d_in[2];
    const float* ctx_b  = (const float*)d_in[3];
    const float* ve_W   = (const float*)d_in[4];
    const float* ve_b   = (const float*)d_in[5];
    const float* sa_in_w  = (const float*)d_in[6];
    const float* sa_in_b  = (const float*)d_in[7];
    const float* sa_out_w = (const float*)d_in[8];
    const float* sa_out_b = (const float*)d_in[9];
    const float* ca_in_w  = (const float*)d_in[10];
    const float* ca_in_b  = (const float*)d_in[11];
    const float* ca_out_w = (const float*)d_in[12];
    const float* ca_out_b = (const float*)d_in[13];
    const float* lin1_w = (const float*)d_in[14];
    const float* lin1_b = (const float*)d_in[15];
    const float* lin2_w = (const float*)d_in[16];
    const float* lin2_b = (const float*)d_in[17];
    const float* ln1_w = (const float*)d_in[18];
    const float* ln1_b = (const float*)d_in[19];
    const float* ln2_w = (const float*)d_in[20];
    const float* ln2_b = (const float*)d_in[21];
    const float* ln3_w = (const float*)d_in[22];
    const float* ln3_b = (const float*)d_in[23];
    const float* o1_w = (const float*)d_in[24];
    const float* o1_b = (const float*)d_in[25];
    const float* o2_w = (const float*)d_in[26];
    const float* o2_b = (const float*)d_in[27];

    float* out = (float*)d_out;                 // [B, P, 1]
    float* ws = (float*)d_ws;

    // workspace layout (floats) — total ~27.2M floats (~109 MB)
    size_t off = 0;
    float* pe      = ws + off; off += (size_t)P * D;            // 12288
    float* vals    = ws + off; off += (size_t)(P + 1) * B;      // 6400
    float* memory  = ws + off; off += (size_t)B * D;
    float* vtmp    = ws + off; off += (size_t)B * D;
    float* ca_add  = ws + off; off += (size_t)L * B * D;
    float* x       = ws + off; off += (size_t)B * D;
    float* qkv     = ws + off; off += (size_t)B * 3 * D;
    float* attn_o  = ws + off; off += (size_t)B * D;
    float* ybuf    = ws + off; off += (size_t)B * D;
    float* hbuf    = ws + off; off += (size_t)B * FF;
    float* hh      = ws + off; off += (size_t)B * 256;
    float* kcache  = ws + off; off += (size_t)L * B * H * P * HD;
    float* vcache  = ws + off; off += (size_t)L * B * H * P * HD;
    (void)ws_size; (void)n_in; (void)in_sizes; (void)out_size;

    const size_t cstride = (size_t)B * H * P * HD;   // per-layer cache stride

    // -------- per-launch setup --------
    pe_kernel<<<P, 256, 0, stream>>>(pe);
    init_vals<<<1, B, 0, stream>>>(vals, start_token);
    // memory = context @ ctx_W.T + ctx_b
    gemm_bias<0, false><<<dim3(4, 8), 256, 0, stream>>>(
        context, ctx_W, ctx_b, memory, B, D, CTX, nullptr, nullptr, 0);
    // ca_add[l] = (memory @ Wv_l.T + bv_l) @ Wo_l.T + bo_l   (T=1 memory!)
    for (int l = 0; l < L; l++) {
        gemm_bias<0, false><<<dim3(4, 8), 256, 0, stream>>>(
            memory, ca_in_w + (size_t)l * 3 * D * D + (size_t)2 * D * D,
            ca_in_b + (size_t)l * 3 * D + 2 * D, vtmp, B, D, D, nullptr, nullptr, 0);
        gemm_bias<0, false><<<dim3(4, 8), 256, 0, stream>>>(
            vtmp, ca_out_w + (size_t)l * D * D, ca_out_b + (size_t)l * D,
            ca_add + (size_t)l * B * D, B, D, D, nullptr, nullptr, 0);
    }

    // -------- autoregressive decode --------
    for (int t = 0; t < P; t++) {
        embed_kernel<<<(B * D) / 256, 256, 0, stream>>>(vals, ve_W, ve_b, pe, x, t);
        for (int l = 0; l < L; l++) {
            float* kc = kcache + (size_t)l * cstride;
            float* vc = vcache + (size_t)l * cstride;
            // QKV projection + KV-cache scatter
            gemm_bias<0, true><<<dim3(4, 24), 256, 0, stream>>>(
                x, sa_in_w + (size_t)l * 3 * D * D, sa_in_b + (size_t)l * 3 * D,
                qkv, B, 3 * D, D, kc, vc, t);
            // causal attention for position t
            attn_kernel<<<B * H, 64, 0, stream>>>(qkv, kc, vc, attn_o, t);
            // output projection
            gemm_bias<0, false><<<dim3(4, 8), 256, 0, stream>>>(
                attn_o, sa_out_w + (size_t)l * D * D, sa_out_b + (size_t)l * D,
                ybuf, B, D, D, nullptr, nullptr, 0);
            // x = LN2(LN1(x + y) + ca_add[l])
            fused_ln<<<B, 256, 0, stream>>>(
                x, ybuf, ca_add + (size_t)l * B * D,
                ln1_w + l * D, ln1_b + l * D, ln2_w + l * D, ln2_b + l * D, x);
            // FFN
            gemm_bias<1, false><<<dim3(4, 32), 256, 0, stream>>>(
                x, lin1_w + (size_t)l * FF * D, lin1_b + (size_t)l * FF,
                hbuf, B, FF, D, nullptr, nullptr, 0);
            gemm_bias<0, false><<<dim3(4, 8), 256, 0, stream>>>(
                hbuf, lin2_w + (size_t)l * D * FF, lin2_b + (size_t)l * D,
                ybuf, B, D, FF, nullptr, nullptr, 0);
            // x = LN3(x + y)
            fused_ln<<<B, 256, 0, stream>>>(
                x, ybuf, nullptr, ln3_w + l * D, ln3_b + l * D,
                nullptr, nullptr, x);
        }
        // output head
        gemm_bias<1, false><<<dim3(4, 4), 256, 0, stream>>>(
            x, o1_w, o1_b, hh, B, 256, D, nullptr, nullptr, 0);
        head2_kernel<<<B, 64, 0, stream>>>(hh, o2_w, o2_b, vals, out, t);
    }
}